// Round 7
// baseline (213.812 us; speedup 1.0000x reference)
//
#include <hip/hip_runtime.h>
#include <hip/hip_bf16.h>
#include <hip/hip_fp16.h>

#define D_MODEL 1024
#define NH 16
#define HD 64
#define BATCH 2
#define SEQ 2048

typedef __attribute__((ext_vector_type(8))) short short8;
typedef __attribute__((ext_vector_type(4))) float floatx4;
typedef __attribute__((ext_vector_type(16))) float floatx16;
typedef __attribute__((ext_vector_type(8))) _Float16 half8;

static __device__ __forceinline__ short f2bf(float f) {
    __hip_bfloat16 h = __float2bfloat16(f);
    return *reinterpret_cast<short*>(&h);
}
static __device__ __forceinline__ unsigned int pk2bf(float a, float b) {
    float2 t; t.x = a; t.y = b;
    __hip_bfloat162 h2 = __float22bfloat162_rn(t);
    return *reinterpret_cast<unsigned int*>(&h2);
}
// v_permlane32_swap_b32: a.hi-lanes <-> b.lo-lanes (in place on both)
static __device__ __forceinline__ void pl32swap(unsigned &a, unsigned &b) {
    asm("v_permlane32_swap_b32 %0, %1" : "+v"(a), "+v"(b));
}
static __device__ __forceinline__ short8 mk8(unsigned a, unsigned b,
                                             unsigned c, unsigned d) {
    union { unsigned u[4]; short8 s; } t;
    t.u[0] = a; t.u[1] = b; t.u[2] = c; t.u[3] = d;
    return t.s;
}

#define GLDS(gp, lp) __builtin_amdgcn_global_load_lds( \
    (const __attribute__((address_space(1))) void*)(gp), \
    (__attribute__((address_space(3))) void*)(lp), 16, 0, 0)

// ---------------------------------------------------------------------------
// fused fp32 -> bf16 convert: x (4M), w_qkv (3M), w_fc (1M)
// ---------------------------------------------------------------------------
__global__ __launch_bounds__(256) void cvt_all(
    const float* __restrict__ x, const float* __restrict__ wq,
    const float* __restrict__ wf,
    short* __restrict__ Xb, short* __restrict__ Wqb, short* __restrict__ Wfb)
{
    int i = blockIdx.x * 256 + threadIdx.x;
    const float* src; short* dst; int off;
    if (i < 524288)      { src = x;  dst = Xb;  off = i; }
    else if (i < 917504) { src = wq; dst = Wqb; off = i - 524288; }
    else                 { src = wf; dst = Wfb; off = i - 917504; }
    float4 a = *reinterpret_cast<const float4*>(src + off * 8);
    float4 b = *reinterpret_cast<const float4*>(src + off * 8 + 4);
    short8 o;
    o[0] = f2bf(a.x); o[1] = f2bf(a.y); o[2] = f2bf(a.z); o[3] = f2bf(a.w);
    o[4] = f2bf(b.x); o[5] = f2bf(b.y); o[6] = f2bf(b.z); o[7] = f2bf(b.w);
    *reinterpret_cast<short8*>(dst + off * 8) = o;
}

// ---------------------------------------------------------------------------
// GEMM1 v2: QKV projection, m97 shape. 128x128 tile, BK=64 (16 K-steps),
// 32 KB LDS total (m132 lesson: BK=128/64KB LDS halves residency -> 339 TF;
// BK=64 target ~874-TF-class structure). global_load_lds(16B) + XOR
// swizzle (fc_gemm-proven), XCD-clustered block mapping.
// Q*0.125*log2e -> [b,h,s,d]; K -> [b,h,s,d]; V -> [b,h,d,s].
// ---------------------------------------------------------------------------
__global__ __launch_bounds__(256) void qkv_gemm(
    const short* __restrict__ X, const short* __restrict__ W,
    const float* __restrict__ bias,
    short* __restrict__ Qs, short* __restrict__ Ks, short* __restrict__ Vt_g)
{
    __shared__ __align__(16) short SH[2][128 * 64];  // As | Bs, 32 KB total
    short* As = &SH[0][0];
    short* Bs = &SH[1][0];
    const int tid = threadIdx.x;

    // XCD-clustered decode
    const int lin = blockIdx.x;
    const int g = lin & 7;
    const int loc = lin >> 3;         // 0..95
    const int mi = loc / 3;           // 0..31
    const int j3 = loc - mi * 3;      // 0..2
    const int m0 = mi * 128;
    const int n0 = (g + 8 * j3) * 128;
    const int bi = m0 >> 11, sl0 = m0 & 2047;

    const int w = tid >> 6, lane = tid & 63;
    const int quad = lane >> 4, l15 = lane & 15;
    const int wm2 = w >> 1, wn2 = w & 1;

    const int rg = lane >> 3;          // row in 8-row group
    const int sl = lane & 7;           // LDS 16B slot
    const int cg = sl ^ rg;            // swizzled global chunk

    floatx4 acc[4][4];
#pragma unroll
    for (int i = 0; i < 4; i++)
#pragma unroll
        for (int j = 0; j < 4; j++) acc[i][j] = (floatx4)0.0f;

    for (int k0 = 0; k0 < 1024; k0 += 64) {
        __syncthreads();
#pragma unroll
        for (int jj = 0; jj < 4; jj++) {
            int grp = w * 4 + jj;              // 16 groups of 8 rows
            int r = grp * 8 + rg;
            GLDS(&X[(size_t)(m0 + r) * 1024 + k0 + cg * 8], &As[grp * 512]);
            GLDS(&W[(size_t)(n0 + r) * 1024 + k0 + cg * 8], &Bs[grp * 512]);
        }
        __syncthreads();
        // LDS addr of (row r, chunk c): (r>>3)*512 + (r&7)*64 + ((c^(r&7))*8)
#pragma unroll
        for (int kk = 0; kk < 2; kk++) {
            const int ch = kk * 4 + quad;      // k-chunk 0..7
            short8 a[4], b[4];
#pragma unroll
            for (int t = 0; t < 4; t++) {
                int ra = wm2 * 64 + t * 16 + l15;
                int rb = wn2 * 64 + t * 16 + l15;
                a[t] = *reinterpret_cast<const short8*>(
                    &As[(ra >> 3) * 512 + (ra & 7) * 64 + ((ch ^ (ra & 7)) * 8)]);
                b[t] = *reinterpret_cast<const short8*>(
                    &Bs[(rb >> 3) * 512 + (rb & 7) * 64 + ((ch ^ (rb & 7)) * 8)]);
            }
#pragma unroll
            for (int mt = 0; mt < 4; mt++)
#pragma unroll
                for (int nt = 0; nt < 4; nt++)
                    acc[mt][nt] = __builtin_amdgcn_mfma_f32_16x16x32_bf16(
                        a[mt], b[nt], acc[mt][nt], 0, 0, 0);
        }
    }

    __syncthreads();
    short* EA = &SH[0][0];   // [128][72] bounce view (9216 shorts, spans As+Bs)
    short* T  = &SH[0][0];   // [64][136] transposed view for V (8704 shorts)
#pragma unroll
    for (int half = 0; half < 2; half++) {
        const int colg0 = n0 + half * 64;
        const int h = colg0 / 192;
        const int t = (colg0 % 192) / 64;
        if (wn2 == half) {
#pragma unroll
            for (int nt = 0; nt < 4; nt++) {
                int jj = nt * 16 + l15;
                float bv = bias[colg0 + jj];
#pragma unroll
                for (int mt = 0; mt < 4; mt++) {
#pragma unroll
                    for (int r = 0; r < 4; r++) {
                        int ml = wm2 * 64 + mt * 16 + quad * 4 + r;
                        float v = acc[mt][nt][r] + bv;
                        if (t == 0) v *= 0.18033688f;   // 0.125 * log2(e)
                        if (t < 2) EA[ml * 72 + jj] = f2bf(v);
                        else       T[jj * 136 + ml] = f2bf(v);
                    }
                }
            }
        }
        __syncthreads();
        if (t < 2) {
            short* dst = (t == 0) ? Qs : Ks;
#pragma unroll
            for (int i = 0; i < 4; i++) {       // 128 rows x 8 chunks
                int c = tid + i * 256;
                int row = c >> 3, ck = c & 7;
                uint4 u = *reinterpret_cast<const uint4*>(&EA[row * 72 + ck * 8]);
                *reinterpret_cast<uint4*>(
                    &dst[((size_t)(bi * NH + h) * SEQ + sl0 + row) * HD + ck * 8]) = u;
            }
        } else {
#pragma unroll
            for (int i = 0; i < 4; i++) {       // 64 d-rows x 16 chunks
                int c = tid + i * 256;
                int d = c >> 4, ck = c & 15;
                uint4 u = *reinterpret_cast<const uint4*>(&T[d * 136 + ck * 8]);
                *reinterpret_cast<uint4*>(
                    &Vt_g[((size_t)(bi * NH + h) * HD + d) * SEQ + sl0 + ck * 8]) = u;
            }
        }
        __syncthreads();
    }
}

// ---------------------------------------------------------------------------
// Flash attention v6 (unchanged from R6, passing): 512-thread blocks
// (8 waves x 32 q), K/V staged in LDS shared by all 8 waves, double-
// buffered, one __syncthreads per 32-k tile. l = fp32 VALU sum.
// NOTE: ~76 us invariant across R1/R5/R6 configs -- limiter unknown,
// needs counters (will reappear in top-5 after qkv fix).
// ---------------------------------------------------------------------------
__global__ __launch_bounds__(512, 4) void attn_kernel(
    const short* __restrict__ Qs, const short* __restrict__ Ks,
    const short* __restrict__ Vt_g,
    _Float16* __restrict__ Opart, float* __restrict__ lpart)
{
    __shared__ __align__(16) short Kl[2][32 * 64];   // 2 x 4 KB
    __shared__ __align__(16) short Vl[2][32 * 64];   // 2 x 4 KB

    const int tid = threadIdx.x;            // 0..511
    const int w = tid >> 6;                 // wave 0..7
    const int lane = tid & 63;
    const int hi = lane >> 5, l31 = lane & 31;

    // decode: xcd = lin&7 fixed for all 8 qblocks of a (khalf,h,bi) group
    const int lin = blockIdx.x;
    const int xcd = lin & 7;
    const int j = lin >> 3;                 // 0..63
    const int qb = j & 7;                   // q-block 0..7 (256 q each)
    const int grp = xcd + 8 * (j >> 3);     // 0..63
    const int khalf = grp & 1;
    const int h = (grp >> 1) & 15;
    const int bi = grp >> 5;
    const int bh = bi * NH + h;
    const int kbase = bh * SEQ * HD;        // K/Q: [s][d]
    const int vbase = bh * HD * SEQ;        // V^T: [d][s]
    const int kt0 = khalf * (SEQ / 2);
    const int qw = qb * 256 + w * 32;       // this wave's 32 q rows

    // staging decode: st in 0..255 -> LDS row/slot, pre-swizzled chunk
    const int st = tid & 255;
    const int sr = st >> 3;                 // LDS row 0..31
    const int ss = st & 7;                  // 16B slot 0..7
    const int cgs = ss ^ (sr & 7);          // global chunk
    const short* kg = Ks + kbase + (size_t)(kt0 + sr) * HD + cgs * 8;
    const short* vg = Vt_g + vbase +
                      (size_t)(sr + (cgs >> 2) * 32) * SEQ + kt0 + (cgs & 3) * 8;

    // Q fragments (B-operand): col = q = l31, k-elem d = c*16 + hi*8 + j
    short8 aq[4];
    {
        const short* qp = Qs + kbase + (size_t)(qw + l31) * HD + hi * 8;
#pragma unroll
        for (int c = 0; c < 4; c++)
            aq[c] = *reinterpret_cast<const short8*>(qp + c * 16);
    }

    floatx16 o0 = (floatx16)0.0f, o1 = (floatx16)0.0f;
    float l_acc = 0.0f;

    // fragment read offsets (shorts): row base + swizzled chunk
    const int rbase = (l31 >> 3) * 512 + (l31 & 7) * 64;
    const int rx = l31 & 7;

    // prologue: stage tile 0 into buffer 0 (waves 0-3 K, waves 4-7 V)
    if (tid < 256) GLDS(kg, &Kl[0][st * 8]);
    else           GLDS(vg, &Vl[0][st * 8]);
    __syncthreads();

    int cur = 0;
    for (int it = 0; it < SEQ / 2 / 32; it++) {   // 32 tiles of 32 k
        // stage tile it+1 into the other buffer (last iter: harmless
        // in-workspace overfetch, never read)
        if (tid < 256) GLDS(kg + (size_t)(it + 1) * (32 * HD), &Kl[cur ^ 1][st * 8]);
        else           GLDS(vg + (it + 1) * 32, &Vl[cur ^ 1][st * 8]);

        // fragment reads from LDS (swizzled)
        const short* Kb = &Kl[cur][0];
        const short* Vb = &Vl[cur][0];
        short8 kf[4], vA0, vA1, vB0, vB1;
#pragma unroll
        for (int c = 0; c < 4; c++)
            kf[c] = *reinterpret_cast<const short8*>(
                Kb + rbase + (((2 * c + hi) ^ rx) * 8));
        vA0 = *reinterpret_cast<const short8*>(Vb + rbase + (((0 + hi) ^ rx) * 8));
        vA1 = *reinterpret_cast<const short8*>(Vb + rbase + (((2 + hi) ^ rx) * 8));
        vB0 = *reinterpret_cast<const short8*>(Vb + rbase + (((4 + hi) ^ rx) * 8));
        vB1 = *reinterpret_cast<const short8*>(Vb + rbase + (((6 + hi) ^ rx) * 8));

        // S^T tile: D[k][q], d-contraction 64 (4 chained MFMAs)
        floatx16 s = (floatx16)0.0f;
        s = __builtin_amdgcn_mfma_f32_32x32x16_bf16(kf[0], aq[0], s, 0, 0, 0);
        s = __builtin_amdgcn_mfma_f32_32x32x16_bf16(kf[1], aq[1], s, 0, 0, 0);
        s = __builtin_amdgcn_mfma_f32_32x32x16_bf16(kf[2], aq[2], s, 0, 0, 0);
        s = __builtin_amdgcn_mfma_f32_32x32x16_bf16(kf[3], aq[3], s, 0, 0, 0);

        float p[16];
#pragma unroll
        for (int r = 0; r < 16; r++) p[r] = exp2f(s[r]);

        // l: fp32 pairwise sum of this lane's 16 P values (k = 16 of the
        // tile's 32; other half via shfl_xor at epilogue)
        {
            float s0 = (p[0] + p[1]) + (p[2] + p[3]);
            float s1 = (p[4] + p[5]) + (p[6] + p[7]);
            float s2 = (p[8] + p[9]) + (p[10] + p[11]);
            float s3 = (p[12] + p[13]) + (p[14] + p[15]);
            l_acc += (s0 + s1) + (s2 + s3);
        }

        // T12: pack pairs, permlane32_swap to PV A-layout (k = hi*8+j)
        unsigned d0a = pk2bf(p[0], p[1]),   d2a = pk2bf(p[4], p[5]);
        unsigned d1a = pk2bf(p[2], p[3]),   d3a = pk2bf(p[6], p[7]);
        pl32swap(d0a, d2a);
        pl32swap(d1a, d3a);
        unsigned d0b = pk2bf(p[8], p[9]),   d2b = pk2bf(p[12], p[13]);
        unsigned d1b = pk2bf(p[10], p[11]), d3b = pk2bf(p[14], p[15]);
        pl32swap(d0b, d2b);
        pl32swap(d1b, d3b);
        short8 pa0 = mk8(d0a, d1a, d2a, d3a);   // k in [0,16)
        short8 pa1 = mk8(d0b, d1b, d2b, d3b);   // k in [16,32)

        // PV
        o0 = __builtin_amdgcn_mfma_f32_32x32x16_bf16(pa0, vA0, o0, 0, 0, 0);
        o1 = __builtin_amdgcn_mfma_f32_32x32x16_bf16(pa0, vB0, o1, 0, 0, 0);
        o0 = __builtin_amdgcn_mfma_f32_32x32x16_bf16(pa1, vA1, o0, 0, 0, 0);
        o1 = __builtin_amdgcn_mfma_f32_32x32x16_bf16(pa1, vB1, o1, 0, 0, 0);

        __syncthreads();   // drains glds (vmcnt) + all lds reads; swap safe
        cur ^= 1;
    }

    // Epilogue: O rows q = (r&3)+8*(r>>2)+4*hi, cols d = dt*32 + l31
#pragma unroll
    for (int r = 0; r < 16; r++) {
        int ql = qw + (r & 3) + 8 * (r >> 2) + 4 * hi;
        size_t base = (size_t)khalf * (4096u * 1024u) +
                      ((size_t)bi * SEQ + ql) * D_MODEL + h * HD;
        Opart[base + l31]      = (_Float16)o0[r];
        Opart[base + 32 + l31] = (_Float16)o1[r];
    }
    // l: lane(l31,hi) holds sum over its 16-k half of every tile
    float l_oth = __shfl_xor(l_acc, 32);
    if (hi == 0)
        lpart[khalf * 65536 + bh * SEQ + qw + l31] = l_acc + l_oth;
}

// ---------------------------------------------------------------------------
// combine: attnb[m][e] = bf16( (O1+O2)/(l1+l2) ). 8 elems/thread.
// ---------------------------------------------------------------------------
__global__ __launch_bounds__(256) void combine_kernel(
    const _Float16* __restrict__ O, const float* __restrict__ lp,
    short* __restrict__ attnb)
{
    int i = blockIdx.x * 256 + threadIdx.x;
    int m = i >> 7;
    int e0 = (i & 127) * 8;
    int bi = m >> 11, s = m & 2047, h = e0 >> 6;
    int bh = bi * NH + h;
    float l = lp[bh * SEQ + s] + lp[65536 + bh * SEQ + s];
    float rl = 1.0f / l;
    size_t off = (size_t)m * D_MODEL + e0;
    half8 a = *reinterpret_cast<const half8*>(O + off);
    half8 b = *reinterpret_cast<const half8*>(O + 4096u * 1024u + off);
    short8 out;
#pragma unroll
    for (int j = 0; j < 8; j++)
        out[j] = f2bf(((float)a[j] + (float)b[j]) * rl);
    *reinterpret_cast<short8*>(attnb + off) = out;
}

// ---------------------------------------------------------------------------
// GEMM2 (R16-exact): 128m x 64n, global_load_lds + XOR swizzle. fp32 out.
// ---------------------------------------------------------------------------
__global__ __launch_bounds__(256) void fc_gemm(
    const short* __restrict__ A, const short* __restrict__ W,
    const float* __restrict__ bias, float* __restrict__ out)
{
    __shared__ __align__(16) short As[128 * 64];
    __shared__ __align__(16) short Bs[64 * 64];
    const int tid = threadIdx.x;
    const int m0 = blockIdx.y * 128;
    const int n0 = blockIdx.x * 64;
    const int w = tid >> 6, lane = tid & 63;
    const int quad = lane >> 4, l15 = lane & 15;
    const int wm2 = w >> 1, wn2 = w & 1;

    const int rg = lane >> 3;
    const int sl = lane & 7;
    const int cg = sl ^ rg;

    floatx4 acc[4][2];
#pragma unroll
    for (int i = 0; i < 4; i++)
#pragma unroll
        for (int j = 0; j < 2; j++) acc[i][j] = (floatx4)0.0f;

    for (int k0 = 0; k0 < 1024; k0 += 64) {
        __syncthreads();
#pragma unroll
        for (int j = 0; j < 4; j++) {
            int g = w * 4 + j;
            int r = g * 8 + rg;
            GLDS(&A[(size_t)(m0 + r) * 1024 + k0 + cg * 8], &As[g * 512]);
        }
#pragma unroll
        for (int j = 0; j < 2; j++) {
            int g = w * 2 + j;
            int r = g * 8 + rg;
            GLDS(&W[(size_t)(n0 + r) * 1024 + k0 + cg * 8], &Bs[g * 512]);
        }
        __syncthreads();
#pragma unroll
        for (int kk = 0; kk < 2; kk++) {
            int swz = ((kk * 4 + quad) ^ (l15 & 7)) * 8;
            short8 a[4], b[2];
#pragma unroll
            for (int i = 0; i < 4; i++)
                a[i] = *reinterpret_cast<const short8*>(
                    &As[(wm2 * 64 + i * 16 + l15) * 64 + swz]);
#pragma unroll
            for (int j = 0; j < 2; j++)
                b[j] = *reinterpret_cast<const short8*>(
                    &Bs[(wn2 * 32 + j * 16 + l15) * 64 + swz]);
#pragma unroll
            for (int mt = 0; mt < 4; mt++)
#pragma unroll
                for (int nt = 0; nt < 2; nt++)
                    acc[mt][nt] = __builtin_amdgcn_mfma_f32_16x16x32_bf16(
                        a[mt], b[nt], acc[mt][nt], 0, 0, 0);
        }
    }

#pragma unroll
    for (int nt = 0; nt < 2; nt++) {
        int col = n0 + wn2 * 32 + nt * 16 + l15;
        float bv = bias[col];
#pragma unroll
        for (int mt = 0; mt < 4; mt++) {
#pragma unroll
            for (int r = 0; r < 4; r++) {
                int row = m0 + wm2 * 64 + mt * 16 + quad * 4 + r;
                out[row * 1024 + col] = acc[mt][nt][r] + bv;
            }
        }
    }
}

extern "C" void kernel_launch(void* const* d_in, const int* in_sizes, int n_in,
                              void* d_out, int out_size, void* d_ws, size_t ws_size,
                              hipStream_t stream) {
    const float* x     = (const float*)d_in[0];
    const float* w_qkv = (const float*)d_in[1];
    const float* b_qkv = (const float*)d_in[2];
    const float* w_fc  = (const float*)d_in[3];
    const float* b_fc  = (const float*)d_in[4];
    float* out = (float*)d_out;

    const size_t M1 = 1024u * 1024u;
    short* ws = (short*)d_ws;
    short* Qs    = ws;
    short* Ks    = ws + 4 * M1;
    short* Vt_g  = ws + 8 * M1;
    short* Wfb   = ws + 12 * M1;
    short* Xb    = ws + 13 * M1;
    short* Wqb   = ws + 17 * M1;
    _Float16* Opart = (_Float16*)(ws + 13 * M1);
    float* lpart = (float*)(ws + 21 * M1);
    short* attnb = Qs;   // Qs dead after attn

    cvt_all<<<4096, 256, 0, stream>>>(x, w_qkv, w_fc, Xb, Wqb, Wfb);
    qkv_gemm<<<768, 256, 0, stream>>>(Xb, Wqb, b_qkv, Qs, Ks, Vt_g);
    attn_kernel<<<512, 512, 0, stream>>>(Qs, Ks, Vt_g, Opart, lpart);
    combine_kernel<<<2048, 256, 0, stream>>>(Opart, lpart, attnb);
    fc_gemm<<<dim3(16, 32), 256, 0, stream>>>(attnb, Wfb, b_fc, out);
}

// Round 8
// 199.825 us; speedup vs baseline: 1.0700x; 1.0700x over previous
//
#include <hip/hip_runtime.h>
#include <hip/hip_bf16.h>
#include <hip/hip_fp16.h>

#define D_MODEL 1024
#define NH 16
#define HD 64
#define BATCH 2
#define SEQ 2048

typedef __attribute__((ext_vector_type(8))) short short8;
typedef __attribute__((ext_vector_type(4))) float floatx4;
typedef __attribute__((ext_vector_type(16))) float floatx16;
typedef __attribute__((ext_vector_type(8))) _Float16 half8;

static __device__ __forceinline__ short f2bf(float f) {
    __hip_bfloat16 h = __float2bfloat16(f);
    return *reinterpret_cast<short*>(&h);
}
static __device__ __forceinline__ unsigned int pk2bf(float a, float b) {
    float2 t; t.x = a; t.y = b;
    __hip_bfloat162 h2 = __float22bfloat162_rn(t);
    return *reinterpret_cast<unsigned int*>(&h2);
}
// v_permlane32_swap_b32: a.hi-lanes <-> b.lo-lanes (in place on both)
static __device__ __forceinline__ void pl32swap(unsigned &a, unsigned &b) {
    asm("v_permlane32_swap_b32 %0, %1" : "+v"(a), "+v"(b));
}
static __device__ __forceinline__ short8 mk8(unsigned a, unsigned b,
                                             unsigned c, unsigned d) {
    union { unsigned u[4]; short8 s; } t;
    t.u[0] = a; t.u[1] = b; t.u[2] = c; t.u[3] = d;
    return t.s;
}

#define GLDS(gp, lp) __builtin_amdgcn_global_load_lds( \
    (const __attribute__((address_space(1))) void*)(gp), \
    (__attribute__((address_space(3))) void*)(lp), 16, 0, 0)

// ---------------------------------------------------------------------------
// fused fp32 -> bf16 convert: x (4M), w_qkv (3M), w_fc (1M)
// ---------------------------------------------------------------------------
__global__ __launch_bounds__(256) void cvt_all(
    const float* __restrict__ x, const float* __restrict__ wq,
    const float* __restrict__ wf,
    short* __restrict__ Xb, short* __restrict__ Wqb, short* __restrict__ Wfb)
{
    int i = blockIdx.x * 256 + threadIdx.x;
    const float* src; short* dst; int off;
    if (i < 524288)      { src = x;  dst = Xb;  off = i; }
    else if (i < 917504) { src = wq; dst = Wqb; off = i - 524288; }
    else                 { src = wf; dst = Wfb; off = i - 917504; }
    float4 a = *reinterpret_cast<const float4*>(src + off * 8);
    float4 b = *reinterpret_cast<const float4*>(src + off * 8 + 4);
    short8 o;
    o[0] = f2bf(a.x); o[1] = f2bf(a.y); o[2] = f2bf(a.z); o[3] = f2bf(a.w);
    o[4] = f2bf(b.x); o[5] = f2bf(b.y); o[6] = f2bf(b.z); o[7] = f2bf(b.w);
    *reinterpret_cast<short8*>(dst + off * 8) = o;
}

// ---------------------------------------------------------------------------
// GEMM1 v3: QKV projection, 2-phase pipelined. 128x128 tile, BK=32,
// DOUBLE-BUFFERED 32 KB LDS: stage(next buf) issued BEFORE compute(cur),
// ONE barrier per step -> prefetch latency hides under compute (the R7
// structure drained vmcnt(0) at a barrier right after issuing loads,
// exposing full L2 latency every K-step; attn_kernel already uses this
// 2-phase pattern successfully).
// Swizzle: chunk ^ (r&3) ^ ((r>>2)&3) (2 XOR bits over 4 chunks/row):
// ds_read_b128 lands max 2-way bank aliasing (free per m136); staging
// source pre-swizzled, LDS dest linear (both-sides rule).
// K-accumulation order identical to R7 (bit-exact output).
// Q*0.125*log2e -> [b,h,s,d]; K -> [b,h,s,d]; V -> [b,h,d,s].
// ---------------------------------------------------------------------------
__global__ __launch_bounds__(256) void qkv_gemm(
    const short* __restrict__ X, const short* __restrict__ W,
    const float* __restrict__ bias,
    short* __restrict__ Qs, short* __restrict__ Ks, short* __restrict__ Vt_g)
{
    // SH[0],SH[1] = A buffers; SH[2],SH[3] = B buffers. 32 KB total.
    __shared__ __align__(16) short SH[4][128 * 32];
    const int tid = threadIdx.x;

    // XCD-clustered decode
    const int lin = blockIdx.x;
    const int g = lin & 7;
    const int loc = lin >> 3;         // 0..95
    const int mi = loc / 3;           // 0..31
    const int j3 = loc - mi * 3;      // 0..2
    const int m0 = mi * 128;
    const int n0 = (g + 8 * j3) * 128;
    const int bi = m0 >> 11, sl0 = m0 & 2047;

    const int w = tid >> 6, lane = tid & 63;
    const int quad = lane >> 4, l15 = lane & 15;
    const int wm2 = w >> 1, wn2 = w & 1;

    // staging: tile = [128 rows][4 x 16B chunks], slot s -> LDS offset s*16B.
    // slot s holds global chunk (s&3) ^ f(r), f(r) = (r&3)^((r>>2)&3).
    const int r1 = tid >> 2,        c1 = tid & 3;
    const int g1 = c1 ^ (r1 & 3) ^ ((r1 >> 2) & 3);
    const int r2 = (tid + 256) >> 2, c2 = tid & 3;   // (tid+256)&3 == tid&3
    const int g2 = c2 ^ (r2 & 3) ^ ((r2 >> 2) & 3);

    const short* Xs1 = X + (size_t)(m0 + r1) * 1024 + g1 * 8;
    const short* Xs2 = X + (size_t)(m0 + r2) * 1024 + g2 * 8;
    const short* Ws1 = W + (size_t)(n0 + r1) * 1024 + g1 * 8;
    const short* Ws2 = W + (size_t)(n0 + r2) * 1024 + g2 * 8;

    // read swizzle: for fragment rows (ra ≡ l15 mod 16), chunk quad:
    // slot chunk = quad ^ (l15&3) ^ ((l15>>2)&3) -- constant per lane.
    const int rsw = (quad ^ (l15 & 3) ^ ((l15 >> 2) & 3)) * 8;

    floatx4 acc[4][4];
#pragma unroll
    for (int i = 0; i < 4; i++)
#pragma unroll
        for (int j = 0; j < 4; j++) acc[i][j] = (floatx4)0.0f;

    // prologue: stage step 0 into buffer 0
    GLDS(Xs1, &SH[0][tid * 8]);
    GLDS(Xs2, &SH[0][(tid + 256) * 8]);
    GLDS(Ws1, &SH[2][tid * 8]);
    GLDS(Ws2, &SH[2][(tid + 256) * 8]);
    __syncthreads();

    int cur = 0;
    for (int step = 0; step < 32; step++) {   // 32 K-steps of 32
        // issue next-step staging FIRST (latency hides under compute;
        // step 31 overfetches harmlessly within d_ws)
        const int kn = (step + 1) * 32;
        GLDS(Xs1 + kn, &SH[cur ^ 1][tid * 8]);
        GLDS(Xs2 + kn, &SH[cur ^ 1][(tid + 256) * 8]);
        GLDS(Ws1 + kn, &SH[2 + (cur ^ 1)][tid * 8]);
        GLDS(Ws2 + kn, &SH[2 + (cur ^ 1)][(tid + 256) * 8]);

        const short* As = &SH[cur][0];
        const short* Bs = &SH[2 + cur][0];
        short8 a[4], b[4];
#pragma unroll
        for (int t = 0; t < 4; t++) {
            int ra = wm2 * 64 + t * 16 + l15;
            int rb = wn2 * 64 + t * 16 + l15;
            a[t] = *reinterpret_cast<const short8*>(&As[ra * 32 + rsw]);
            b[t] = *reinterpret_cast<const short8*>(&Bs[rb * 32 + rsw]);
        }
#pragma unroll
        for (int mt = 0; mt < 4; mt++)
#pragma unroll
            for (int nt = 0; nt < 4; nt++)
                acc[mt][nt] = __builtin_amdgcn_mfma_f32_16x16x32_bf16(
                    a[mt], b[nt], acc[mt][nt], 0, 0, 0);

        __syncthreads();   // drains next-stage glds (landed during compute)
        cur ^= 1;
    }

    __syncthreads();
    short* EA = &SH[0][0];   // [128][72] bounce view (9216 shorts of 16384)
    short* T  = &SH[0][0];   // [64][136] transposed view for V (8704 shorts)
#pragma unroll
    for (int half = 0; half < 2; half++) {
        const int colg0 = n0 + half * 64;
        const int h = colg0 / 192;
        const int t = (colg0 % 192) / 64;
        if (wn2 == half) {
#pragma unroll
            for (int nt = 0; nt < 4; nt++) {
                int jj = nt * 16 + l15;
                float bv = bias[colg0 + jj];
#pragma unroll
                for (int mt = 0; mt < 4; mt++) {
#pragma unroll
                    for (int r = 0; r < 4; r++) {
                        int ml = wm2 * 64 + mt * 16 + quad * 4 + r;
                        float v = acc[mt][nt][r] + bv;
                        if (t == 0) v *= 0.18033688f;   // 0.125 * log2(e)
                        if (t < 2) EA[ml * 72 + jj] = f2bf(v);
                        else       T[jj * 136 + ml] = f2bf(v);
                    }
                }
            }
        }
        __syncthreads();
        if (t < 2) {
            short* dst = (t == 0) ? Qs : Ks;
#pragma unroll
            for (int i = 0; i < 4; i++) {       // 128 rows x 8 chunks
                int c = tid + i * 256;
                int row = c >> 3, ck = c & 7;
                uint4 u = *reinterpret_cast<const uint4*>(&EA[row * 72 + ck * 8]);
                *reinterpret_cast<uint4*>(
                    &dst[((size_t)(bi * NH + h) * SEQ + sl0 + row) * HD + ck * 8]) = u;
            }
        } else {
#pragma unroll
            for (int i = 0; i < 4; i++) {       // 64 d-rows x 16 chunks
                int c = tid + i * 256;
                int d = c >> 4, ck = c & 15;
                uint4 u = *reinterpret_cast<const uint4*>(&T[d * 136 + ck * 8]);
                *reinterpret_cast<uint4*>(
                    &Vt_g[((size_t)(bi * NH + h) * HD + d) * SEQ + sl0 + ck * 8]) = u;
            }
        }
        __syncthreads();
    }
}

// ---------------------------------------------------------------------------
// Flash attention v6 (unchanged, passing): 512-thread blocks (8 waves x
// 32 q), K/V staged in LDS shared by all 8 waves, double-buffered, one
// __syncthreads per 32-k tile. l = fp32 VALU sum.
// ~76 us: VALU/trans-pipe-throughput-bound (R5 2w/SIMD == R6 4w/SIMD).
// ---------------------------------------------------------------------------
__global__ __launch_bounds__(512, 4) void attn_kernel(
    const short* __restrict__ Qs, const short* __restrict__ Ks,
    const short* __restrict__ Vt_g,
    _Float16* __restrict__ Opart, float* __restrict__ lpart)
{
    __shared__ __align__(16) short Kl[2][32 * 64];   // 2 x 4 KB
    __shared__ __align__(16) short Vl[2][32 * 64];   // 2 x 4 KB

    const int tid = threadIdx.x;            // 0..511
    const int w = tid >> 6;                 // wave 0..7
    const int lane = tid & 63;
    const int hi = lane >> 5, l31 = lane & 31;

    // decode: xcd = lin&7 fixed for all 8 qblocks of a (khalf,h,bi) group
    const int lin = blockIdx.x;
    const int xcd = lin & 7;
    const int j = lin >> 3;                 // 0..63
    const int qb = j & 7;                   // q-block 0..7 (256 q each)
    const int grp = xcd + 8 * (j >> 3);     // 0..63
    const int khalf = grp & 1;
    const int h = (grp >> 1) & 15;
    const int bi = grp >> 5;
    const int bh = bi * NH + h;
    const int kbase = bh * SEQ * HD;        // K/Q: [s][d]
    const int vbase = bh * HD * SEQ;        // V^T: [d][s]
    const int kt0 = khalf * (SEQ / 2);
    const int qw = qb * 256 + w * 32;       // this wave's 32 q rows

    // staging decode: st in 0..255 -> LDS row/slot, pre-swizzled chunk
    const int st = tid & 255;
    const int sr = st >> 3;                 // LDS row 0..31
    const int ss = st & 7;                  // 16B slot 0..7
    const int cgs = ss ^ (sr & 7);          // global chunk
    const short* kg = Ks + kbase + (size_t)(kt0 + sr) * HD + cgs * 8;
    const short* vg = Vt_g + vbase +
                      (size_t)(sr + (cgs >> 2) * 32) * SEQ + kt0 + (cgs & 3) * 8;

    // Q fragments (B-operand): col = q = l31, k-elem d = c*16 + hi*8 + j
    short8 aq[4];
    {
        const short* qp = Qs + kbase + (size_t)(qw + l31) * HD + hi * 8;
#pragma unroll
        for (int c = 0; c < 4; c++)
            aq[c] = *reinterpret_cast<const short8*>(qp + c * 16);
    }

    floatx16 o0 = (floatx16)0.0f, o1 = (floatx16)0.0f;
    float l_acc = 0.0f;

    // fragment read offsets (shorts): row base + swizzled chunk
    const int rbase = (l31 >> 3) * 512 + (l31 & 7) * 64;
    const int rx = l31 & 7;

    // prologue: stage tile 0 into buffer 0 (waves 0-3 K, waves 4-7 V)
    if (tid < 256) GLDS(kg, &Kl[0][st * 8]);
    else           GLDS(vg, &Vl[0][st * 8]);
    __syncthreads();

    int cur = 0;
    for (int it = 0; it < SEQ / 2 / 32; it++) {   // 32 tiles of 32 k
        // stage tile it+1 into the other buffer (last iter: harmless
        // in-workspace overfetch, never read)
        if (tid < 256) GLDS(kg + (size_t)(it + 1) * (32 * HD), &Kl[cur ^ 1][st * 8]);
        else           GLDS(vg + (it + 1) * 32, &Vl[cur ^ 1][st * 8]);

        // fragment reads from LDS (swizzled)
        const short* Kb = &Kl[cur][0];
        const short* Vb = &Vl[cur][0];
        short8 kf[4], vA0, vA1, vB0, vB1;
#pragma unroll
        for (int c = 0; c < 4; c++)
            kf[c] = *reinterpret_cast<const short8*>(
                Kb + rbase + (((2 * c + hi) ^ rx) * 8));
        vA0 = *reinterpret_cast<const short8*>(Vb + rbase + (((0 + hi) ^ rx) * 8));
        vA1 = *reinterpret_cast<const short8*>(Vb + rbase + (((2 + hi) ^ rx) * 8));
        vB0 = *reinterpret_cast<const short8*>(Vb + rbase + (((4 + hi) ^ rx) * 8));
        vB1 = *reinterpret_cast<const short8*>(Vb + rbase + (((6 + hi) ^ rx) * 8));

        // S^T tile: D[k][q], d-contraction 64 (4 chained MFMAs)
        floatx16 s = (floatx16)0.0f;
        s = __builtin_amdgcn_mfma_f32_32x32x16_bf16(kf[0], aq[0], s, 0, 0, 0);
        s = __builtin_amdgcn_mfma_f32_32x32x16_bf16(kf[1], aq[1], s, 0, 0, 0);
        s = __builtin_amdgcn_mfma_f32_32x32x16_bf16(kf[2], aq[2], s, 0, 0, 0);
        s = __builtin_amdgcn_mfma_f32_32x32x16_bf16(kf[3], aq[3], s, 0, 0, 0);

        float p[16];
#pragma unroll
        for (int r = 0; r < 16; r++) p[r] = exp2f(s[r]);

        // l: fp32 pairwise sum of this lane's 16 P values (k = 16 of the
        // tile's 32; other half via shfl_xor at epilogue)
        {
            float s0 = (p[0] + p[1]) + (p[2] + p[3]);
            float s1 = (p[4] + p[5]) + (p[6] + p[7]);
            float s2 = (p[8] + p[9]) + (p[10] + p[11]);
            float s3 = (p[12] + p[13]) + (p[14] + p[15]);
            l_acc += (s0 + s1) + (s2 + s3);
        }

        // T12: pack pairs, permlane32_swap to PV A-layout (k = hi*8+j)
        unsigned d0a = pk2bf(p[0], p[1]),   d2a = pk2bf(p[4], p[5]);
        unsigned d1a = pk2bf(p[2], p[3]),   d3a = pk2bf(p[6], p[7]);
        pl32swap(d0a, d2a);
        pl32swap(d1a, d3a);
        unsigned d0b = pk2bf(p[8], p[9]),   d2b = pk2bf(p[12], p[13]);
        unsigned d1b = pk2bf(p[10], p[11]), d3b = pk2bf(p[14], p[15]);
        pl32swap(d0b, d2b);
        pl32swap(d1b, d3b);
        short8 pa0 = mk8(d0a, d1a, d2a, d3a);   // k in [0,16)
        short8 pa1 = mk8(d0b, d1b, d2b, d3b);   // k in [16,32)

        // PV
        o0 = __builtin_amdgcn_mfma_f32_32x32x16_bf16(pa0, vA0, o0, 0, 0, 0);
        o1 = __builtin_amdgcn_mfma_f32_32x32x16_bf16(pa0, vB0, o1, 0, 0, 0);
        o0 = __builtin_amdgcn_mfma_f32_32x32x16_bf16(pa1, vA1, o0, 0, 0, 0);
        o1 = __builtin_amdgcn_mfma_f32_32x32x16_bf16(pa1, vB1, o1, 0, 0, 0);

        __syncthreads();   // drains glds (vmcnt) + all lds reads; swap safe
        cur ^= 1;
    }

    // Epilogue: O rows q = (r&3)+8*(r>>2)+4*hi, cols d = dt*32 + l31
#pragma unroll
    for (int r = 0; r < 16; r++) {
        int ql = qw + (r & 3) + 8 * (r >> 2) + 4 * hi;
        size_t base = (size_t)khalf * (4096u * 1024u) +
                      ((size_t)bi * SEQ + ql) * D_MODEL + h * HD;
        Opart[base + l31]      = (_Float16)o0[r];
        Opart[base + 32 + l31] = (_Float16)o1[r];
    }
    // l: lane(l31,hi) holds sum over its 16-k half of every tile
    float l_oth = __shfl_xor(l_acc, 32);
    if (hi == 0)
        lpart[khalf * 65536 + bh * SEQ + qw + l31] = l_acc + l_oth;
}

// ---------------------------------------------------------------------------
// combine: attnb[m][e] = bf16( (O1+O2)/(l1+l2) ). 8 elems/thread.
// ---------------------------------------------------------------------------
__global__ __launch_bounds__(256) void combine_kernel(
    const _Float16* __restrict__ O, const float* __restrict__ lp,
    short* __restrict__ attnb)
{
    int i = blockIdx.x * 256 + threadIdx.x;
    int m = i >> 7;
    int e0 = (i & 127) * 8;
    int bi = m >> 11, s = m & 2047, h = e0 >> 6;
    int bh = bi * NH + h;
    float l = lp[bh * SEQ + s] + lp[65536 + bh * SEQ + s];
    float rl = 1.0f / l;
    size_t off = (size_t)m * D_MODEL + e0;
    half8 a = *reinterpret_cast<const half8*>(O + off);
    half8 b = *reinterpret_cast<const half8*>(O + 4096u * 1024u + off);
    short8 out;
#pragma unroll
    for (int j = 0; j < 8; j++)
        out[j] = f2bf(((float)a[j] + (float)b[j]) * rl);
    *reinterpret_cast<short8*>(attnb + off) = out;
}

// ---------------------------------------------------------------------------
// GEMM2 (R16-exact): 128m x 64n, global_load_lds + XOR swizzle. fp32 out.
// ---------------------------------------------------------------------------
__global__ __launch_bounds__(256) void fc_gemm(
    const short* __restrict__ A, const short* __restrict__ W,
    const float* __restrict__ bias, float* __restrict__ out)
{
    __shared__ __align__(16) short As[128 * 64];
    __shared__ __align__(16) short Bs[64 * 64];
    const int tid = threadIdx.x;
    const int m0 = blockIdx.y * 128;
    const int n0 = blockIdx.x * 64;
    const int w = tid >> 6, lane = tid & 63;
    const int quad = lane >> 4, l15 = lane & 15;
    const int wm2 = w >> 1, wn2 = w & 1;

    const int rg = lane >> 3;
    const int sl = lane & 7;
    const int cg = sl ^ rg;

    floatx4 acc[4][2];
#pragma unroll
    for (int i = 0; i < 4; i++)
#pragma unroll
        for (int j = 0; j < 2; j++) acc[i][j] = (floatx4)0.0f;

    for (int k0 = 0; k0 < 1024; k0 += 64) {
        __syncthreads();
#pragma unroll
        for (int j = 0; j < 4; j++) {
            int g = w * 4 + j;
            int r = g * 8 + rg;
            GLDS(&A[(size_t)(m0 + r) * 1024 + k0 + cg * 8], &As[g * 512]);
        }
#pragma unroll
        for (int j = 0; j < 2; j++) {
            int g = w * 2 + j;
            int r = g * 8 + rg;
            GLDS(&W[(size_t)(n0 + r) * 1024 + k0 + cg * 8], &Bs[g * 512]);
        }
        __syncthreads();
#pragma unroll
        for (int kk = 0; kk < 2; kk++) {
            int swz = ((kk * 4 + quad) ^ (l15 & 7)) * 8;
            short8 a[4], b[2];
#pragma unroll
            for (int i = 0; i < 4; i++)
                a[i] = *reinterpret_cast<const short8*>(
                    &As[(wm2 * 64 + i * 16 + l15) * 64 + swz]);
#pragma unroll
            for (int j = 0; j < 2; j++)
                b[j] = *reinterpret_cast<const short8*>(
                    &Bs[(wn2 * 32 + j * 16 + l15) * 64 + swz]);
#pragma unroll
            for (int mt = 0; mt < 4; mt++)
#pragma unroll
                for (int nt = 0; nt < 2; nt++)
                    acc[mt][nt] = __builtin_amdgcn_mfma_f32_16x16x32_bf16(
                        a[mt], b[nt], acc[mt][nt], 0, 0, 0);
        }
    }

#pragma unroll
    for (int nt = 0; nt < 2; nt++) {
        int col = n0 + wn2 * 32 + nt * 16 + l15;
        float bv = bias[col];
#pragma unroll
        for (int mt = 0; mt < 4; mt++) {
#pragma unroll
            for (int r = 0; r < 4; r++) {
                int row = m0 + wm2 * 64 + mt * 16 + quad * 4 + r;
                out[row * 1024 + col] = acc[mt][nt][r] + bv;
            }
        }
    }
}

extern "C" void kernel_launch(void* const* d_in, const int* in_sizes, int n_in,
                              void* d_out, int out_size, void* d_ws, size_t ws_size,
                              hipStream_t stream) {
    const float* x     = (const float*)d_in[0];
    const float* w_qkv = (const float*)d_in[1];
    const float* b_qkv = (const float*)d_in[2];
    const float* w_fc  = (const float*)d_in[3];
    const float* b_fc  = (const float*)d_in[4];
    float* out = (float*)d_out;

    const size_t M1 = 1024u * 1024u;
    short* ws = (short*)d_ws;
    short* Qs    = ws;
    short* Ks    = ws + 4 * M1;
    short* Vt_g  = ws + 8 * M1;
    short* Wfb   = ws + 12 * M1;
    short* Xb    = ws + 13 * M1;
    short* Wqb   = ws + 17 * M1;
    _Float16* Opart = (_Float16*)(ws + 13 * M1);
    float* lpart = (float*)(ws + 21 * M1);
    short* attnb = Qs;   // Qs dead after attn

    cvt_all<<<4096, 256, 0, stream>>>(x, w_qkv, w_fc, Xb, Wqb, Wfb);
    qkv_gemm<<<768, 256, 0, stream>>>(Xb, Wqb, b_qkv, Qs, Ks, Vt_g);
    attn_kernel<<<512, 512, 0, stream>>>(Qs, Ks, Vt_g, Opart, lpart);
    combine_kernel<<<2048, 256, 0, stream>>>(Opart, lpart, attnb);
    fc_gemm<<<dim3(16, 32), 256, 0, stream>>>(attnb, Wfb, b_fc, out);
}

// Round 10
// 186.337 us; speedup vs baseline: 1.1474x; 1.0724x over previous
//
#include <hip/hip_runtime.h>
#include <hip/hip_bf16.h>
#include <hip/hip_fp16.h>

#define D_MODEL 1024
#define NH 16
#define HD 64
#define BATCH 2
#define SEQ 2048

typedef __attribute__((ext_vector_type(8))) short short8;
typedef __attribute__((ext_vector_type(4))) float floatx4;
typedef __attribute__((ext_vector_type(16))) float floatx16;
typedef __attribute__((ext_vector_type(8))) _Float16 half8;

static __device__ __forceinline__ short f2bf(float f) {
    __hip_bfloat16 h = __float2bfloat16(f);
    return *reinterpret_cast<short*>(&h);
}
static __device__ __forceinline__ unsigned int pk2bf(float a, float b) {
    float2 t; t.x = a; t.y = b;
    __hip_bfloat162 h2 = __float22bfloat162_rn(t);
    return *reinterpret_cast<unsigned int*>(&h2);
}
// v_permlane32_swap_b32: a.hi-lanes <-> b.lo-lanes (in place on both)
static __device__ __forceinline__ void pl32swap(unsigned &a, unsigned &b) {
    asm("v_permlane32_swap_b32 %0, %1" : "+v"(a), "+v"(b));
}
static __device__ __forceinline__ short8 mk8(unsigned a, unsigned b,
                                             unsigned c, unsigned d) {
    union { unsigned u[4]; short8 s; } t;
    t.u[0] = a; t.u[1] = b; t.u[2] = c; t.u[3] = d;
    return t.s;
}
// fast 2^x: __builtin_amdgcn_exp2f emits bare v_exp_f32 THROUGH the
// compiler (hazard nops + scheduling handled -- R9's opaque inline-asm
// version dropped TRANS-pipe wait states -> sporadic stale reads,
// absmax 8e-3). No libm range-fixup expansion (R8: that was ~40% of
// attn VALUBusy); our |S| is far from the fixup range.
static __device__ __forceinline__ float fexp2(float x) {
    return __builtin_amdgcn_exp2f(x);
}

#define GLDS(gp, lp) __builtin_amdgcn_global_load_lds( \
    (const __attribute__((address_space(1))) void*)(gp), \
    (__attribute__((address_space(3))) void*)(lp), 16, 0, 0)

// ---------------------------------------------------------------------------
// fused fp32 -> bf16 convert: x (4M), w_qkv (3M), w_fc (1M)
// ---------------------------------------------------------------------------
__global__ __launch_bounds__(256) void cvt_all(
    const float* __restrict__ x, const float* __restrict__ wq,
    const float* __restrict__ wf,
    short* __restrict__ Xb, short* __restrict__ Wqb, short* __restrict__ Wfb)
{
    int i = blockIdx.x * 256 + threadIdx.x;
    const float* src; short* dst; int off;
    if (i < 524288)      { src = x;  dst = Xb;  off = i; }
    else if (i < 917504) { src = wq; dst = Wqb; off = i - 524288; }
    else                 { src = wf; dst = Wfb; off = i - 917504; }
    float4 a = *reinterpret_cast<const float4*>(src + off * 8);
    float4 b = *reinterpret_cast<const float4*>(src + off * 8 + 4);
    short8 o;
    o[0] = f2bf(a.x); o[1] = f2bf(a.y); o[2] = f2bf(a.z); o[3] = f2bf(a.w);
    o[4] = f2bf(b.x); o[5] = f2bf(b.y); o[6] = f2bf(b.z); o[7] = f2bf(b.w);
    *reinterpret_cast<short8*>(dst + off * 8) = o;
}

// ---------------------------------------------------------------------------
// GEMM1 v3 (R8, passing): QKV projection, 2-phase pipelined. 128x128 tile,
// BK=32, double-buffered 32 KB LDS: stage(next) issued BEFORE compute(cur),
// one barrier per step. Swizzle chunk ^ (r&3) ^ ((r>>2)&3).
// Q*0.125*log2e -> [b,h,s,d]; K -> [b,h,s,d]; V -> [b,h,d,s].
// ---------------------------------------------------------------------------
__global__ __launch_bounds__(256) void qkv_gemm(
    const short* __restrict__ X, const short* __restrict__ W,
    const float* __restrict__ bias,
    short* __restrict__ Qs, short* __restrict__ Ks, short* __restrict__ Vt_g)
{
    // SH[0],SH[1] = A buffers; SH[2],SH[3] = B buffers. 32 KB total.
    __shared__ __align__(16) short SH[4][128 * 32];
    const int tid = threadIdx.x;

    // XCD-clustered decode
    const int lin = blockIdx.x;
    const int g = lin & 7;
    const int loc = lin >> 3;         // 0..95
    const int mi = loc / 3;           // 0..31
    const int j3 = loc - mi * 3;      // 0..2
    const int m0 = mi * 128;
    const int n0 = (g + 8 * j3) * 128;
    const int bi = m0 >> 11, sl0 = m0 & 2047;

    const int w = tid >> 6, lane = tid & 63;
    const int quad = lane >> 4, l15 = lane & 15;
    const int wm2 = w >> 1, wn2 = w & 1;

    // staging: tile = [128 rows][4 x 16B chunks], slot s -> LDS offset s*16B.
    // slot s holds global chunk (s&3) ^ f(r), f(r) = (r&3)^((r>>2)&3).
    const int r1 = tid >> 2,        c1 = tid & 3;
    const int g1 = c1 ^ (r1 & 3) ^ ((r1 >> 2) & 3);
    const int r2 = (tid + 256) >> 2, c2 = tid & 3;   // (tid+256)&3 == tid&3
    const int g2 = c2 ^ (r2 & 3) ^ ((r2 >> 2) & 3);

    const short* Xs1 = X + (size_t)(m0 + r1) * 1024 + g1 * 8;
    const short* Xs2 = X + (size_t)(m0 + r2) * 1024 + g2 * 8;
    const short* Ws1 = W + (size_t)(n0 + r1) * 1024 + g1 * 8;
    const short* Ws2 = W + (size_t)(n0 + r2) * 1024 + g2 * 8;

    // read swizzle: slot chunk = quad ^ (l15&3) ^ ((l15>>2)&3), const/lane.
    const int rsw = (quad ^ (l15 & 3) ^ ((l15 >> 2) & 3)) * 8;

    floatx4 acc[4][4];
#pragma unroll
    for (int i = 0; i < 4; i++)
#pragma unroll
        for (int j = 0; j < 4; j++) acc[i][j] = (floatx4)0.0f;

    // prologue: stage step 0 into buffer 0
    GLDS(Xs1, &SH[0][tid * 8]);
    GLDS(Xs2, &SH[0][(tid + 256) * 8]);
    GLDS(Ws1, &SH[2][tid * 8]);
    GLDS(Ws2, &SH[2][(tid + 256) * 8]);
    __syncthreads();

    int cur = 0;
    for (int step = 0; step < 32; step++) {   // 32 K-steps of 32
        // issue next-step staging FIRST (latency hides under compute;
        // step 31 overfetches harmlessly within d_ws)
        const int kn = (step + 1) * 32;
        GLDS(Xs1 + kn, &SH[cur ^ 1][tid * 8]);
        GLDS(Xs2 + kn, &SH[cur ^ 1][(tid + 256) * 8]);
        GLDS(Ws1 + kn, &SH[2 + (cur ^ 1)][tid * 8]);
        GLDS(Ws2 + kn, &SH[2 + (cur ^ 1)][(tid + 256) * 8]);

        const short* As = &SH[cur][0];
        const short* Bs = &SH[2 + cur][0];
        short8 a[4], b[4];
#pragma unroll
        for (int t = 0; t < 4; t++) {
            int ra = wm2 * 64 + t * 16 + l15;
            int rb = wn2 * 64 + t * 16 + l15;
            a[t] = *reinterpret_cast<const short8*>(&As[ra * 32 + rsw]);
            b[t] = *reinterpret_cast<const short8*>(&Bs[rb * 32 + rsw]);
        }
#pragma unroll
        for (int mt = 0; mt < 4; mt++)
#pragma unroll
            for (int nt = 0; nt < 4; nt++)
                acc[mt][nt] = __builtin_amdgcn_mfma_f32_16x16x32_bf16(
                    a[mt], b[nt], acc[mt][nt], 0, 0, 0);

        __syncthreads();   // drains next-stage glds (landed during compute)
        cur ^= 1;
    }

    __syncthreads();
    short* EA = &SH[0][0];   // [128][72] bounce view (9216 shorts of 16384)
    short* T  = &SH[0][0];   // [64][136] transposed view for V (8704 shorts)
#pragma unroll
    for (int half = 0; half < 2; half++) {
        const int colg0 = n0 + half * 64;
        const int h = colg0 / 192;
        const int t = (colg0 % 192) / 64;
        if (wn2 == half) {
#pragma unroll
            for (int nt = 0; nt < 4; nt++) {
                int jj = nt * 16 + l15;
                float bv = bias[colg0 + jj];
#pragma unroll
                for (int mt = 0; mt < 4; mt++) {
#pragma unroll
                    for (int r = 0; r < 4; r++) {
                        int ml = wm2 * 64 + mt * 16 + quad * 4 + r;
                        float v = acc[mt][nt][r] + bv;
                        if (t == 0) v *= 0.18033688f;   // 0.125 * log2(e)
                        if (t < 2) EA[ml * 72 + jj] = f2bf(v);
                        else       T[jj * 136 + ml] = f2bf(v);
                    }
                }
            }
        }
        __syncthreads();
        if (t < 2) {
            short* dst = (t == 0) ? Qs : Ks;
#pragma unroll
            for (int i = 0; i < 4; i++) {       // 128 rows x 8 chunks
                int c = tid + i * 256;
                int row = c >> 3, ck = c & 7;
                uint4 u = *reinterpret_cast<const uint4*>(&EA[row * 72 + ck * 8]);
                *reinterpret_cast<uint4*>(
                    &dst[((size_t)(bi * NH + h) * SEQ + sl0 + row) * HD + ck * 8]) = u;
            }
        } else {
#pragma unroll
            for (int i = 0; i < 4; i++) {       // 64 d-rows x 16 chunks
                int c = tid + i * 256;
                int d = c >> 4, ck = c & 15;
                uint4 u = *reinterpret_cast<const uint4*>(&T[d * 136 + ck * 8]);
                *reinterpret_cast<uint4*>(
                    &Vt_g[((size_t)(bi * NH + h) * HD + d) * SEQ + sl0 + ck * 8]) = u;
            }
        }
        __syncthreads();
    }
}

// ---------------------------------------------------------------------------
// Flash attention v8: R8 structure (512 threads, 8 waves x 32 q, K/V LDS
// double-buffer, 1 barrier/tile) + VALU diet:
//  - exp via __builtin_amdgcn_exp2f (bare v_exp_f32, compiler-scheduled)
//  - l via ones-MFMA (R5-proven): adds move to the 20%-idle matrix pipe.
// ---------------------------------------------------------------------------
__global__ __launch_bounds__(512, 4) void attn_kernel(
    const short* __restrict__ Qs, const short* __restrict__ Ks,
    const short* __restrict__ Vt_g,
    _Float16* __restrict__ Opart, float* __restrict__ lpart)
{
    __shared__ __align__(16) short Kl[2][32 * 64];   // 2 x 4 KB
    __shared__ __align__(16) short Vl[2][32 * 64];   // 2 x 4 KB

    const int tid = threadIdx.x;            // 0..511
    const int w = tid >> 6;                 // wave 0..7
    const int lane = tid & 63;
    const int hi = lane >> 5, l31 = lane & 31;

    // decode: xcd = lin&7 fixed for all 8 qblocks of a (khalf,h,bi) group
    const int lin = blockIdx.x;
    const int xcd = lin & 7;
    const int j = lin >> 3;                 // 0..63
    const int qb = j & 7;                   // q-block 0..7 (256 q each)
    const int grp = xcd + 8 * (j >> 3);     // 0..63
    const int khalf = grp & 1;
    const int h = (grp >> 1) & 15;
    const int bi = grp >> 5;
    const int bh = bi * NH + h;
    const int kbase = bh * SEQ * HD;        // K/Q: [s][d]
    const int vbase = bh * HD * SEQ;        // V^T: [d][s]
    const int kt0 = khalf * (SEQ / 2);
    const int qw = qb * 256 + w * 32;       // this wave's 32 q rows

    // staging decode: st in 0..255 -> LDS row/slot, pre-swizzled chunk
    const int st = tid & 255;
    const int sr = st >> 3;                 // LDS row 0..31
    const int ss = st & 7;                  // 16B slot 0..7
    const int cgs = ss ^ (sr & 7);          // global chunk
    const short* kg = Ks + kbase + (size_t)(kt0 + sr) * HD + cgs * 8;
    const short* vg = Vt_g + vbase +
                      (size_t)(sr + (cgs >> 2) * 32) * SEQ + kt0 + (cgs & 3) * 8;

    const short8 onesv = {(short)0x3F80, (short)0x3F80, (short)0x3F80, (short)0x3F80,
                          (short)0x3F80, (short)0x3F80, (short)0x3F80, (short)0x3F80};

    // Q fragments (B-operand): col = q = l31, k-elem d = c*16 + hi*8 + j
    short8 aq[4];
    {
        const short* qp = Qs + kbase + (size_t)(qw + l31) * HD + hi * 8;
#pragma unroll
        for (int c = 0; c < 4; c++)
            aq[c] = *reinterpret_cast<const short8*>(qp + c * 16);
    }

    floatx16 o0 = (floatx16)0.0f, o1 = (floatx16)0.0f, ol = (floatx16)0.0f;

    // fragment read offsets (shorts): row base + swizzled chunk
    const int rbase = (l31 >> 3) * 512 + (l31 & 7) * 64;
    const int rx = l31 & 7;

    // prologue: stage tile 0 into buffer 0 (waves 0-3 K, waves 4-7 V)
    if (tid < 256) GLDS(kg, &Kl[0][st * 8]);
    else           GLDS(vg, &Vl[0][st * 8]);
    __syncthreads();

    int cur = 0;
    for (int it = 0; it < SEQ / 2 / 32; it++) {   // 32 tiles of 32 k
        // stage tile it+1 into the other buffer (last iter: harmless
        // in-workspace overfetch, never read)
        if (tid < 256) GLDS(kg + (size_t)(it + 1) * (32 * HD), &Kl[cur ^ 1][st * 8]);
        else           GLDS(vg + (it + 1) * 32, &Vl[cur ^ 1][st * 8]);

        // fragment reads from LDS (swizzled)
        const short* Kb = &Kl[cur][0];
        const short* Vb = &Vl[cur][0];
        short8 kf[4], vA0, vA1, vB0, vB1;
#pragma unroll
        for (int c = 0; c < 4; c++)
            kf[c] = *reinterpret_cast<const short8*>(
                Kb + rbase + (((2 * c + hi) ^ rx) * 8));
        vA0 = *reinterpret_cast<const short8*>(Vb + rbase + (((0 + hi) ^ rx) * 8));
        vA1 = *reinterpret_cast<const short8*>(Vb + rbase + (((2 + hi) ^ rx) * 8));
        vB0 = *reinterpret_cast<const short8*>(Vb + rbase + (((4 + hi) ^ rx) * 8));
        vB1 = *reinterpret_cast<const short8*>(Vb + rbase + (((6 + hi) ^ rx) * 8));

        // S^T tile: D[k][q], d-contraction 64 (4 chained MFMAs)
        floatx16 s = (floatx16)0.0f;
        s = __builtin_amdgcn_mfma_f32_32x32x16_bf16(kf[0], aq[0], s, 0, 0, 0);
        s = __builtin_amdgcn_mfma_f32_32x32x16_bf16(kf[1], aq[1], s, 0, 0, 0);
        s = __builtin_amdgcn_mfma_f32_32x32x16_bf16(kf[2], aq[2], s, 0, 0, 0);
        s = __builtin_amdgcn_mfma_f32_32x32x16_bf16(kf[3], aq[3], s, 0, 0, 0);

        float p[16];
#pragma unroll
        for (int r = 0; r < 16; r++) p[r] = fexp2(s[r]);

        // T12: pack pairs, permlane32_swap to PV A-layout (k = hi*8+j)
        unsigned d0a = pk2bf(p[0], p[1]),   d2a = pk2bf(p[4], p[5]);
        unsigned d1a = pk2bf(p[2], p[3]),   d3a = pk2bf(p[6], p[7]);
        pl32swap(d0a, d2a);
        pl32swap(d1a, d3a);
        unsigned d0b = pk2bf(p[8], p[9]),   d2b = pk2bf(p[12], p[13]);
        unsigned d1b = pk2bf(p[10], p[11]), d3b = pk2bf(p[14], p[15]);
        pl32swap(d0b, d2b);
        pl32swap(d1b, d3b);
        short8 pa0 = mk8(d0a, d1a, d2a, d3a);   // k in [0,16)
        short8 pa1 = mk8(d0b, d1b, d2b, d3b);   // k in [16,32)

        // PV + l (ones-MFMA on the idle matrix pipe)
        o0 = __builtin_amdgcn_mfma_f32_32x32x16_bf16(pa0, vA0, o0, 0, 0, 0);
        o1 = __builtin_amdgcn_mfma_f32_32x32x16_bf16(pa0, vB0, o1, 0, 0, 0);
        o0 = __builtin_amdgcn_mfma_f32_32x32x16_bf16(pa1, vA1, o0, 0, 0, 0);
        o1 = __builtin_amdgcn_mfma_f32_32x32x16_bf16(pa1, vB1, o1, 0, 0, 0);
        ol = __builtin_amdgcn_mfma_f32_32x32x16_bf16(pa0, onesv, ol, 0, 0, 0);
        ol = __builtin_amdgcn_mfma_f32_32x32x16_bf16(pa1, onesv, ol, 0, 0, 0);

        __syncthreads();   // drains glds (vmcnt) + all lds reads; swap safe
        cur ^= 1;
    }

    // Epilogue: O rows q = (r&3)+8*(r>>2)+4*hi, cols d = dt*32 + l31
#pragma unroll
    for (int r = 0; r < 16; r++) {
        int ql = qw + (r & 3) + 8 * (r >> 2) + 4 * hi;
        size_t base = (size_t)khalf * (4096u * 1024u) +
                      ((size_t)bi * SEQ + ql) * D_MODEL + h * HD;
        Opart[base + l31]      = (_Float16)o0[r];
        Opart[base + 32 + l31] = (_Float16)o1[r];
        if (l31 == 0)
            lpart[khalf * 65536 + bh * SEQ + ql] = ol[r];
    }
}

// ---------------------------------------------------------------------------
// combine: attnb[m][e] = bf16( (O1+O2)/(l1+l2) ). 8 elems/thread.
// ---------------------------------------------------------------------------
__global__ __launch_bounds__(256) void combine_kernel(
    const _Float16* __restrict__ O, const float* __restrict__ lp,
    short* __restrict__ attnb)
{
    int i = blockIdx.x * 256 + threadIdx.x;
    int m = i >> 7;
    int e0 = (i & 127) * 8;
    int bi = m >> 11, s = m & 2047, h = e0 >> 6;
    int bh = bi * NH + h;
    float l = lp[bh * SEQ + s] + lp[65536 + bh * SEQ + s];
    float rl = 1.0f / l;
    size_t off = (size_t)m * D_MODEL + e0;
    half8 a = *reinterpret_cast<const half8*>(O + off);
    half8 b = *reinterpret_cast<const half8*>(O + 4096u * 1024u + off);
    short8 out;
#pragma unroll
    for (int j = 0; j < 8; j++)
        out[j] = f2bf(((float)a[j] + (float)b[j]) * rl);
    *reinterpret_cast<short8*>(attnb + off) = out;
}

// ---------------------------------------------------------------------------
// GEMM2 (R16-exact): 128m x 64n, global_load_lds + XOR swizzle. fp32 out.
// ---------------------------------------------------------------------------
__global__ __launch_bounds__(256) void fc_gemm(
    const short* __restrict__ A, const short* __restrict__ W,
    const float* __restrict__ bias, float* __restrict__ out)
{
    __shared__ __align__(16) short As[128 * 64];
    __shared__ __align__(16) short Bs[64 * 64];
    const int tid = threadIdx.x;
    const int m0 = blockIdx.y * 128;
    const int n0 = blockIdx.x * 64;
    const int w = tid >> 6, lane = tid & 63;
    const int quad = lane >> 4, l15 = lane & 15;
    const int wm2 = w >> 1, wn2 = w & 1;

    const int rg = lane >> 3;
    const int sl = lane & 7;
    const int cg = sl ^ rg;

    floatx4 acc[4][2];
#pragma unroll
    for (int i = 0; i < 4; i++)
#pragma unroll
        for (int j = 0; j < 2; j++) acc[i][j] = (floatx4)0.0f;

    for (int k0 = 0; k0 < 1024; k0 += 64) {
        __syncthreads();
#pragma unroll
        for (int j = 0; j < 4; j++) {
            int g = w * 4 + j;
            int r = g * 8 + rg;
            GLDS(&A[(size_t)(m0 + r) * 1024 + k0 + cg * 8], &As[g * 512]);
        }
#pragma unroll
        for (int j = 0; j < 2; j++) {
            int g = w * 2 + j;
            int r = g * 8 + rg;
            GLDS(&W[(size_t)(n0 + r) * 1024 + k0 + cg * 8], &Bs[g * 512]);
        }
        __syncthreads();
#pragma unroll
        for (int kk = 0; kk < 2; kk++) {
            int swz = ((kk * 4 + quad) ^ (l15 & 7)) * 8;
            short8 a[4], b[2];
#pragma unroll
            for (int i = 0; i < 4; i++)
                a[i] = *reinterpret_cast<const short8*>(
                    &As[(wm2 * 64 + i * 16 + l15) * 64 + swz]);
#pragma unroll
            for (int j = 0; j < 2; j++)
                b[j] = *reinterpret_cast<const short8*>(
                    &Bs[(wn2 * 32 + j * 16 + l15) * 64 + swz]);
#pragma unroll
            for (int mt = 0; mt < 4; mt++)
#pragma unroll
                for (int nt = 0; nt < 2; nt++)
                    acc[mt][nt] = __builtin_amdgcn_mfma_f32_16x16x32_bf16(
                        a[mt], b[nt], acc[mt][nt], 0, 0, 0);
        }
    }

#pragma unroll
    for (int nt = 0; nt < 2; nt++) {
        int col = n0 + wn2 * 32 + nt * 16 + l15;
        float bv = bias[col];
#pragma unroll
        for (int mt = 0; mt < 4; mt++) {
#pragma unroll
            for (int r = 0; r < 4; r++) {
                int row = m0 + wm2 * 64 + mt * 16 + quad * 4 + r;
                out[row * 1024 + col] = acc[mt][nt][r] + bv;
            }
        }
    }
}

extern "C" void kernel_launch(void* const* d_in, const int* in_sizes, int n_in,
                              void* d_out, int out_size, void* d_ws, size_t ws_size,
                              hipStream_t stream) {
    const float* x     = (const float*)d_in[0];
    const float* w_qkv = (const float*)d_in[1];
    const float* b_qkv = (const float*)d_in[2];
    const float* w_fc  = (const float*)d_in[3];
    const float* b_fc  = (const float*)d_in[4];
    float* out = (float*)d_out;

    const size_t M1 = 1024u * 1024u;
    short* ws = (short*)d_ws;
    short* Qs    = ws;
    short* Ks    = ws + 4 * M1;
    short* Vt_g  = ws + 8 * M1;
    short* Wfb   = ws + 12 * M1;
    short* Xb    = ws + 13 * M1;
    short* Wqb   = ws + 17 * M1;
    _Float16* Opart = (_Float16*)(ws + 13 * M1);
    float* lpart = (float*)(ws + 21 * M1);
    short* attnb = Qs;   // Qs dead after attn

    cvt_all<<<4096, 256, 0, stream>>>(x, w_qkv, w_fc, Xb, Wqb, Wfb);
    qkv_gemm<<<768, 256, 0, stream>>>(Xb, Wqb, b_qkv, Qs, Ks, Vt_g);
    attn_kernel<<<512, 512, 0, stream>>>(Qs, Ks, Vt_g, Opart, lpart);
    combine_kernel<<<2048, 256, 0, stream>>>(Opart, lpart, attnb);
    fc_gemm<<<dim3(16, 32), 256, 0, stream>>>(attnb, Wfb, b_fc, out);
}